// Round 13
// baseline (649.084 us; speedup 1.0000x reference)
//
#include <hip/hip_runtime.h>

#define BB 4
#define HH 352
#define WW 1216
#define HW (HH * WW)
#define NPIX (BB * HW)   // 1,712,128

// Padded propagation buffer: apron of zeros so bilinear gathers need no
// bounds checks. |rel| <= 4 (encode clamp) => corners in [y-4,y+5]x[x-4,x+5].
#define PAD_T 5
#define PAD_L 8
#define HP (HH + 2 * PAD_T)      // 362
#define WP (WW + 2 * PAD_L)      // 1232
#define HWP (HP * WP)            // 445,984

// Prop LDS tile: block covers 64x4 px; samples live in 13 rows x 73 cols;
// stride 76 (R8: LDS gathers via ds_read2, -2us/step vs global gathers).
#define TROWS 13
#define TCOLS 76
#define TSIZE (TROWS * TCOLS)    // 988

// AoS tap-table record, 16 u32 (64 B) per pixel:
//   [0..7]  : packed coords for neighbors n=0..7, q=round((rel+4)*8192),
//             y low 16, x high 16 (res 1.2e-4 px; absmax ~2048 vs 15729).
//   [8..11] : affinity u16 pairs BY TAP k: (k0|k1<<16)(k2|k3<<16)
//             (k4|k5<<16)(k6|k7<<16); q=round((a+1)*20000), res 5e-5.
//             CENTER tap k=4 is word[10] LOW half (R11/R12 bug: used high).
//   [12]    : k8 affinity in low 16. [13..15] pad.
// Neighbor n -> prop tap k = (n<4 ? n : n+1).
// Why AoS (R13): prop reads the whole record with 3x uint4 + 1x dword =
// 4 VMEM instrs/px vs 17 plane loads. R7 (-26% bytes -> 0) and R8
// (-33 gathers -> -7%) showed prop is issue/transaction-bound, not
// byte-bound; +24 MB/step of pad is irrelevant.
//
// NOTES carried forward:
//  R3 : register arrays MUST use compile-time indices only (else scratch).
//  R5 : WRITE_SIZE includes ~160 MB of 0xAA-poison writeback. Accumulators
//       > real-VGPR budget get AGPR-shuffled (v_accvgpr moves eat VALU):
//       R6 offsets pass VGPR=52 vs 64-float acc -> hence TX=2 (acc<=32).
//  R9-R12: persistent/cooperative single-kernel prop ABANDONED: all-zero
//       output signature = silent launch rejection (empty stream syncs OK);
//       mechanism not identified from outside. Also R11/R12 had a center-tap
//       decode bug (see above). Do not retry without a diagnostic path.

#define OTX 2
#define OTHREADS 640   // 608 active = WW/2

// ---------------------------------------------------------------------------
// Kernel A1: offsets pass — 3x3 conv ch 0..15 -> coord words [0..7] of rec.
// One image row per block (XCD-swizzled), 2 px/thread, acc[16][2]=32 floats.
// Channel mapping (verified R2): neighbor n: dy = ch[2n], dx = ch[2n+1].
// ---------------------------------------------------------------------------
__global__ __launch_bounds__(OTHREADS) void conv_offsets_kernel(
    const float* __restrict__ guid, const float* __restrict__ w,
    const float* __restrict__ bias, unsigned* __restrict__ tab)
{
    int tid = threadIdx.x;
    if (tid >= WW / OTX) return;           // 608 active
    int bid = blockIdx.x;                  // 0..1407, swizzle: 176 rows/XCD
    int row = (bid & 7) * 176 + (bid >> 3);
    int y = row % HH;
    int b = row / HH;
    int x0 = tid * OTX;
    const float* gb = guid + (size_t)b * 8 * HW;

    float acc[16][OTX];
#pragma unroll
    for (int o = 0; o < 16; ++o) {
        float bv = bias[o];
#pragma unroll
        for (int tx = 0; tx < OTX; ++tx) acc[o][tx] = bv;
    }

#pragma unroll 1
    for (int c = 0; c < 8; ++c) {
        // cols x0-1 .. x0+2 of 3 rows
        float g[3][4];
#pragma unroll
        for (int r = 0; r < 3; ++r) {
            int yy = y + r - 1;
            bool rv = (yy >= 0) && (yy < HH);   // uniform per block
            const float* gr = gb + (size_t)c * HW + (size_t)yy * WW;
            if (rv) {
                const float2 m = *(const float2*)(gr + x0);   // 8B aligned
                g[r][1] = m.x; g[r][2] = m.y;
                g[r][0] = (x0 > 0) ? gr[x0 - 1] : 0.f;
                g[r][3] = (x0 + OTX < WW) ? gr[x0 + OTX] : 0.f;
            } else {
#pragma unroll
                for (int i = 0; i < 4; ++i) g[r][i] = 0.f;
            }
        }
#pragma unroll
        for (int r = 0; r < 3; ++r) {
#pragma unroll
            for (int i = 0; i < 3; ++i) {
                int tap = r * 3 + i;
#pragma unroll
                for (int o = 0; o < 16; ++o) {
                    float wv = w[o * 72 + c * 9 + tap];  // uniform -> s_load
#pragma unroll
                    for (int tx = 0; tx < OTX; ++tx)
                        acc[o][tx] = fmaf(wv, g[r][i + tx], acc[o][tx]);
                }
            }
        }
    }

    int idx0 = row * WW + x0;
#pragma unroll
    for (int tx = 0; tx < OTX; ++tx) {
        unsigned cw[8];
#pragma unroll
        for (int n = 0; n < 8; ++n) {
            int k = (n < 4) ? n : n + 1;
            float ky = (float)(k / 3 - 1), kx = (float)(k % 3 - 1);
            float yr = ky + acc[2 * n][tx];
            float xr = kx + acc[2 * n + 1][tx];
            int yq = (int)lrintf((yr + 4.f) * 8192.f);
            int xq = (int)lrintf((xr + 4.f) * 8192.f);
            yq = min(max(yq, 0), 65535);
            xq = min(max(xq, 0), 65535);
            cw[n] = (unsigned)yq | ((unsigned)xq << 16);
        }
        unsigned* rec = tab + (size_t)(idx0 + tx) * 16;
        *(uint4*)(rec)     = make_uint4(cw[0], cw[1], cw[2], cw[3]);
        *(uint4*)(rec + 4) = make_uint4(cw[4], cw[5], cw[6], cw[7]);
    }
}

// ---------------------------------------------------------------------------
// Kernel A2: affinity pass — 3x3 conv ch 16..23 + TGASS -> words [8..12].
// 2 px/thread, acc[8][2]=16 floats.
// ---------------------------------------------------------------------------
__global__ __launch_bounds__(OTHREADS) void conv_aff_kernel(
    const float* __restrict__ guid, const float* __restrict__ w,
    const float* __restrict__ bias, const float* __restrict__ scale_p,
    unsigned* __restrict__ tab)
{
    int tid = threadIdx.x;
    if (tid >= WW / OTX) return;
    int bid = blockIdx.x;
    int row = (bid & 7) * 176 + (bid >> 3);
    int y = row % HH;
    int b = row / HH;
    int x0 = tid * OTX;
    const float* gb = guid + (size_t)b * 8 * HW;

    float acc[8][OTX];
#pragma unroll
    for (int o = 0; o < 8; ++o) {
        float bv = bias[16 + o];
#pragma unroll
        for (int tx = 0; tx < OTX; ++tx) acc[o][tx] = bv;
    }

#pragma unroll 1
    for (int c = 0; c < 8; ++c) {
        float g[3][4];
#pragma unroll
        for (int r = 0; r < 3; ++r) {
            int yy = y + r - 1;
            bool rv = (yy >= 0) && (yy < HH);
            const float* gr = gb + (size_t)c * HW + (size_t)yy * WW;
            if (rv) {
                const float2 m = *(const float2*)(gr + x0);
                g[r][1] = m.x; g[r][2] = m.y;
                g[r][0] = (x0 > 0) ? gr[x0 - 1] : 0.f;
                g[r][3] = (x0 + OTX < WW) ? gr[x0 + OTX] : 0.f;
            } else {
#pragma unroll
                for (int i = 0; i < 4; ++i) g[r][i] = 0.f;
            }
        }
#pragma unroll
        for (int r = 0; r < 3; ++r) {
#pragma unroll
            for (int i = 0; i < 3; ++i) {
                int tap = r * 3 + i;
#pragma unroll
                for (int o = 0; o < 8; ++o) {
                    float wv = w[(16 + o) * 72 + c * 9 + tap];
#pragma unroll
                    for (int tx = 0; tx < OTX; ++tx)
                        acc[o][tx] = fmaf(wv, g[r][i + tx], acc[o][tx]);
                }
            }
        }
    }

    float sc = scale_p[0] + 1e-8f;
    int idx0 = row * WW + x0;

#pragma unroll
    for (int tx = 0; tx < OTX; ++tx) {
        float a[8];
        float asum = 1e-4f;
#pragma unroll
        for (int n = 0; n < 8; ++n) {
            a[n] = tanhf(acc[n][tx]) / sc;
            asum += fabsf(a[n]);
        }
        asum = fmaxf(asum, 1.0f);
        float ssum = 0.f;
#pragma unroll
        for (int n = 0; n < 8; ++n) { a[n] = a[n] / asum; ssum += a[n]; }
        float aref = 1.0f - ssum;

        unsigned av[9];   // by tap k; k=4 is the reference (center)
#pragma unroll
        for (int k = 0; k < 9; ++k) {
            float aval = (k == 4) ? aref : a[(k < 4) ? k : k - 1];
            int q = (int)lrintf((aval + 1.f) * 20000.f);
            av[k] = (unsigned)min(max(q, 0), 65535);
        }
        unsigned* rec = tab + (size_t)(idx0 + tx) * 16;
        *(uint4*)(rec + 8) = make_uint4(av[0] | (av[1] << 16),
                                        av[2] | (av[3] << 16),
                                        av[4] | (av[5] << 16),   // k4 = LOW
                                        av[6] | (av[7] << 16));
        rec[12] = av[8];
    }
}

// ---------------------------------------------------------------------------
// Kernel B: one propagation step (R8 structure, AoS table loads).
// Block = 64x4 px; feat tile (13x76) staged in LDS (ds_read2 gathers).
// XCD swizzle: xcd = bid&7 owns 11 contiguous 4-row y-bands -> featc slice
// L2-resident (R6). Center tap k=4 exact: one LDS read, no lerp.
// ---------------------------------------------------------------------------
template <bool MULCONF>
__global__ __launch_bounds__(256) void prop_step_kernel(
    const float* __restrict__ fsrc, const unsigned* __restrict__ tab,
    const float* __restrict__ conf, float* __restrict__ dst)
{
    __shared__ float tile[TSIZE];

    int bid = blockIdx.x;                 // 6688 blocks = 8 * 836
    int xcd = bid & 7;
    int s = bid >> 3;                     // 0..835
    int yband = xcd * 11 + s % 11;        // 0..87
    int rest = s / 11;                    // 0..75
    int xb = rest % 19;
    int b = rest / 19;
    int t = threadIdx.x;
    int lx = t & 63, ly = t >> 6;
    int x = xb * 64 + lx;
    int y = yband * 4 + ly;
    int idx = (b * HH + y) * WW + x;

    // One AoS record: 3x uint4 + 1 dword (hoisted before the staging barrier)
    const uint4* rp = (const uint4*)(tab + (size_t)idx * 16);
    uint4 c0 = rp[0];                     // cw n0..3
    uint4 c1 = rp[1];                     // cw n4..7
    uint4 au = rp[2];                     // aff pairs (k0,k1)(k2,k3)(k4,k5)(k6,k7)
    unsigned a8 = tab[(size_t)idx * 16 + 12];
    float cv = MULCONF ? conf[idx] : 0.f;

    // Stage tile: padded rows [yband*4+1 .. +53], cols [xb*64+4 .. +76].
    {
        const float* gsrc = fsrc + (size_t)b * HWP
                          + (size_t)(yband * 4 + 1) * WP + (xb * 64 + 4);
        for (int i = t; i < TSIZE; i += 256)
            tile[i] = gsrc[(i / TCOLS) * WP + (i % TCOLS)];
    }
    __syncthreads();

    unsigned cwv[8] = {c0.x, c0.y, c0.z, c0.w, c1.x, c1.y, c1.z, c1.w};
    unsigned akU[9] = {au.x & 0xffffu, au.x >> 16, au.y & 0xffffu, au.y >> 16,
                       au.z & 0xffffu, au.z >> 16, au.w & 0xffffu, au.w >> 16,
                       a8 & 0xffffu};

    float fy = (float)ly;
    float fx = (float)lx;
    float a4 = fmaf((float)akU[4], 5e-5f, -1.f);
    float res = a4 * tile[(ly + 4) * TCOLS + (lx + 4)];   // exact center tap
#pragma unroll
    for (int n = 0; n < 8; ++n) {
        int k = (n < 4) ? n : n + 1;
        float ak = fmaf((float)akU[k], 5e-5f, -1.f);
        unsigned q = cwv[n];
        float ys = fmaf((float)(q & 0xffffu), 1.f / 8192.f, fy);
        float xs = fmaf((float)(q >> 16),     1.f / 8192.f, fx);
        float y0f = floorf(ys), x0f = floorf(xs);
        float wy1 = ys - y0f, wx1 = xs - x0f;
        float wy0 = 1.f - wy1, wx0 = 1.f - wx1;
        int o = (int)y0f * TCOLS + (int)x0f;
        float v00 = tile[o],         v01 = tile[o + 1];          // ds_read2
        float v10 = tile[o + TCOLS], v11 = tile[o + TCOLS + 1];  // ds_read2
        float sv = wy0 * (wx0 * v00 + wx1 * v01) + wy1 * (wx0 * v10 + wx1 * v11);
        res = fmaf(ak, sv, res);
    }
    if (MULCONF) {
        res *= cv;
        dst[(size_t)b * HWP + (y + PAD_T) * WP + (x + PAD_L)] = res;
    } else {
        dst[idx] = res;
    }
}

// Zero both padded buffers (apron must be 0; ws is poisoned 0xAA each launch).
__global__ __launch_bounds__(256) void zero_kernel(float4* __restrict__ p, int n4)
{
    int i = blockIdx.x * blockDim.x + threadIdx.x;
    if (i < n4) p[i] = make_float4(0.f, 0.f, 0.f, 0.f);
}

// fc0[padded interior] = feat_init * conf
__global__ __launch_bounds__(256) void mulpad_kernel(
    const float* __restrict__ a, const float* __restrict__ c, float* __restrict__ o)
{
    int t = threadIdx.x;
    int x = blockIdx.x * 64 + (t & 63);
    int y = blockIdx.y * 4 + (t >> 6);
    int b = blockIdx.z;
    int idx = (b * HH + y) * WW + x;
    o[(size_t)b * HWP + (y + PAD_T) * WP + (x + PAD_L)] = a[idx] * c[idx];
}

extern "C" void kernel_launch(void* const* d_in, const int* in_sizes, int n_in,
                              void* d_out, int out_size, void* d_ws, size_t ws_size,
                              hipStream_t stream)
{
    const float* feat_init  = (const float*)d_in[0];
    const float* guidance   = (const float*)d_in[1];
    const float* confidence = (const float*)d_in[2];
    const float* w_oa       = (const float*)d_in[3];
    const float* b_oa       = (const float*)d_in[4];
    const float* aff_scale  = (const float*)d_in[5];
    float* out = (float*)d_out;

    // Workspace: tab u32[16N] (109.6 MB) | fc0p f32[BB*HWP] | fc1p
    const size_t N = (size_t)NPIX;
    unsigned* tab = (unsigned*)d_ws;
    float* fc0 = (float*)(tab + 16 * N);
    float* fc1 = fc0 + (size_t)BB * HWP;

    const dim3 mgrid(WW / 64, HH / 4, BB);
    const int n4 = 2 * BB * HWP / 4;
    zero_kernel<<<(n4 + 255) / 256, 256, 0, stream>>>((float4*)fc0, n4);
    mulpad_kernel<<<mgrid, 256, 0, stream>>>(feat_init, confidence, fc0);
    conv_offsets_kernel<<<BB * HH, OTHREADS, 0, stream>>>(
        guidance, w_oa, b_oa, tab);
    conv_aff_kernel<<<BB * HH, OTHREADS, 0, stream>>>(
        guidance, w_oa, b_oa, aff_scale, tab);

    const int pblocks = (WW / 64) * (HH / 4) * BB;   // 6688
    float* bufs[2] = {fc0, fc1};
    const int T = 18;
    for (int i = 0; i < T; ++i) {
        const float* src = bufs[i & 1];
        if (i < T - 1) {
            float* dst = bufs[(i + 1) & 1];
            prop_step_kernel<true><<<pblocks, 256, 0, stream>>>(
                src, tab, confidence, dst);
        } else {
            prop_step_kernel<false><<<pblocks, 256, 0, stream>>>(
                src, tab, confidence, out);
        }
    }
}

// Round 14
// 629.483 us; speedup vs baseline: 1.0311x; 1.0311x over previous
//
#include <hip/hip_runtime.h>

#define BB 4
#define HH 352
#define WW 1216
#define HW (HH * WW)
#define NPIX (BB * HW)   // 1,712,128

// Padded propagation buffer: apron of zeros so bilinear gathers need no
// bounds checks. |rel| <= 4 (encode clamp) => corners in [y-4,y+5]x[x-4,x+5].
#define PAD_T 5
#define PAD_L 8
#define HP (HH + 2 * PAD_T)      // 362
#define WP (WW + 2 * PAD_L)      // 1232
#define HWP (HP * WP)            // 445,984

// Prop LDS tile: block covers 64x4 px; samples live in 13 rows x 73 cols;
// stride 76 (R8-verified: 25.1 us/step).
#define TROWS 13
#define TCOLS 76
#define TSIZE (TROWS * TCOLS)    // 988

// Conv LDS tile: 8 ch x 6 rows x 66 cols (12.7 KB), covers a 64x4 px block's
// 3x3 receptive field.
#define GT_W 66
#define GT_CH 396                // 6*66
#define GT_SIZE (8 * GT_CH)      // 3168

// SoA tap tables (R8 format, 50 B/px — verified 25.1 us/step):
//   affp  [9][NPIX] u16 : modulation, q=round((a+1)*20000), res 5e-5.
//   coordp[8][NPIX] u32 : packed coords, q=round((rel+4)*8192), y lo, x hi.
// Neighbor n -> prop tap k = (n<4 ? n : n+1).
//
// NOTES carried forward:
//  R3 : register arrays MUST use compile-time indices only (else scratch).
//  R5/R13: multi-px conv accumulators get AGPR-shuffled regardless of
//       __launch_bounds__ or TX (R13: TX=2 -> VGPR=28, occupancy 36%,
//       97.8 us). Hence R14: 1 px/thread, acc[24] only, LDS-staged guidance.
//  R7/R8/R13: prop pinned at ~25 us/step, insensitive to table bytes
//       (85->138 MB) and VMEM instr count (17->4). AoS (64B/px) REGRESSED
//       (+2.5 us/step): extra bytes cost more than saved issues. Keep R8.
//  R9-R12: persistent/cooperative single-kernel prop ABANDONED (silent
//       all-zero failure, mechanism unidentified; also had a center-tap
//       decode bug). Do not retry without a diagnostic path.
//  (open) prop counters never observed — top-5 always conv dispatches.

// ---------------------------------------------------------------------------
// Kernel A: fused 3x3 conv (8->24 ch, zero pad) + TGASS -> R8-format tables.
// Block = 64x4 px (256 thr), 1 px/thread; guidance staged in LDS.
// Channel mapping (verified R2): neighbor n: dy = ch[2n], dx = ch[2n+1];
// affinity = ch[16+n].
// ---------------------------------------------------------------------------
__global__ __launch_bounds__(256) void conv_fused_kernel(
    const float* __restrict__ guid, const float* __restrict__ w,
    const float* __restrict__ bias, const float* __restrict__ scale_p,
    unsigned short* __restrict__ affp, unsigned* __restrict__ coordp)
{
    __shared__ float gt[GT_SIZE];

    int bx = blockIdx.x, by = blockIdx.y, b = blockIdx.z;
    int t = threadIdx.x;
    int lx = t & 63, ly = t >> 6;
    int x = bx * 64 + lx;
    int y = by * 4 + ly;

    // Stage guidance tile: rows by*4-1 .. by*4+4, cols bx*64-1 .. bx*64+64.
    {
        const float* gb = guid + (size_t)b * 8 * HW;
        int gy0 = by * 4 - 1, gx0 = bx * 64 - 1;
        for (int i = t; i < GT_SIZE; i += 256) {
            int c = i / GT_CH, rem = i - c * GT_CH;
            int r = rem / GT_W, col = rem - r * GT_W;
            int gy = gy0 + r, gx = gx0 + col;
            float v = 0.f;
            if (gy >= 0 && gy < HH && gx >= 0 && gx < WW)
                v = gb[(size_t)c * HW + gy * WW + gx];
            gt[i] = v;
        }
    }
    __syncthreads();

    float acc[24];
#pragma unroll
    for (int o = 0; o < 24; ++o) acc[o] = bias[o];

#pragma unroll 1
    for (int c = 0; c < 8; ++c) {
        float v[9];
#pragma unroll
        for (int r = 0; r < 3; ++r)
#pragma unroll
            for (int i = 0; i < 3; ++i)
                v[r * 3 + i] = gt[c * GT_CH + (ly + r) * GT_W + lx + i];
#pragma unroll
        for (int tap = 0; tap < 9; ++tap) {
#pragma unroll
            for (int o = 0; o < 24; ++o)
                acc[o] = fmaf(w[o * 72 + c * 9 + tap], v[tap], acc[o]);
        }
    }

    // TGASS: tanh / scale, L1-normalize (clamped >= 1), ref = 1 - sum
    float sc = scale_p[0] + 1e-8f;
    float a[8];
    float asum = 1e-4f;
#pragma unroll
    for (int n = 0; n < 8; ++n) {
        a[n] = tanhf(acc[16 + n]) / sc;
        asum += fabsf(a[n]);
    }
    asum = fmaxf(asum, 1.0f);
    float ssum = 0.f;
#pragma unroll
    for (int n = 0; n < 8; ++n) { a[n] = a[n] / asum; ssum += a[n]; }
    float aref = 1.0f - ssum;

    int idx = (b * HH + y) * WW + x;
#pragma unroll
    for (int n = 0; n < 8; ++n) {
        int k = (n < 4) ? n : n + 1;
        float ky = (float)(k / 3 - 1), kx = (float)(k % 3 - 1);
        float yr = ky + acc[2 * n];        // dy = ch[2n]
        float xr = kx + acc[2 * n + 1];    // dx = ch[2n+1]
        int yq = (int)lrintf((yr + 4.f) * 8192.f);
        int xq = (int)lrintf((xr + 4.f) * 8192.f);
        yq = min(max(yq, 0), 65535);
        xq = min(max(xq, 0), 65535);
        coordp[(size_t)n * NPIX + idx] = (unsigned)yq | ((unsigned)xq << 16);
    }
#pragma unroll
    for (int k = 0; k < 9; ++k) {
        float aval = (k == 4) ? aref : a[(k < 4) ? k : k - 1];
        int q = (int)lrintf((aval + 1.f) * 20000.f);
        q = min(max(q, 0), 65535);
        affp[(size_t)k * NPIX + idx] = (unsigned short)q;
    }
}

// ---------------------------------------------------------------------------
// Kernel B: one propagation step (EXACT R8 structure — verified 25.1 us/step).
// Block = 64x4 px; feat tile (13x76) staged in LDS (ds_read2 gathers).
// XCD swizzle: xcd = bid&7 owns 11 contiguous 4-row y-bands -> featc slice
// L2-resident (R6). Center tap k=4 exact: one LDS read, no lerp.
// ---------------------------------------------------------------------------
template <bool MULCONF>
__global__ __launch_bounds__(256) void prop_step_kernel(
    const float* __restrict__ fsrc, const unsigned short* __restrict__ affp,
    const unsigned* __restrict__ coordp, const float* __restrict__ conf,
    float* __restrict__ dst)
{
    __shared__ float tile[TSIZE];

    int bid = blockIdx.x;                 // 6688 blocks = 8 * 836
    int xcd = bid & 7;
    int s = bid >> 3;                     // 0..835
    int yband = xcd * 11 + s % 11;        // 0..87
    int rest = s / 11;                    // 0..75
    int xb = rest % 19;
    int b = rest / 19;
    int t = threadIdx.x;
    int lx = t & 63, ly = t >> 6;
    int x = xb * 64 + lx;
    int y = yband * 4 + ly;
    int idx = (b * HH + y) * WW + x;

    // Hoist independent table loads so they fly across the staging barrier.
    unsigned cw[8];
#pragma unroll
    for (int n = 0; n < 8; ++n) cw[n] = coordp[(size_t)n * NPIX + idx];
    float ak[9];
#pragma unroll
    for (int k = 0; k < 9; ++k)
        ak[k] = fmaf((float)affp[(size_t)k * NPIX + idx], 5e-5f, -1.f);
    float cv = MULCONF ? conf[idx] : 0.f;

    // Stage tile: padded rows [yband*4+1 .. +53], cols [xb*64+4 .. +76].
    {
        const float* gsrc = fsrc + (size_t)b * HWP
                          + (size_t)(yband * 4 + 1) * WP + (xb * 64 + 4);
        for (int i = t; i < TSIZE; i += 256)
            tile[i] = gsrc[(i / TCOLS) * WP + (i % TCOLS)];
    }
    __syncthreads();

    float fy = (float)ly;
    float fx = (float)lx;
    float res = ak[4] * tile[(ly + 4) * TCOLS + (lx + 4)];  // exact center tap
#pragma unroll
    for (int n = 0; n < 8; ++n) {
        float ys = fmaf((float)(cw[n] & 0xffffu), 1.f / 8192.f, fy);
        float xs = fmaf((float)(cw[n] >> 16),     1.f / 8192.f, fx);
        float y0f = floorf(ys), x0f = floorf(xs);
        float wy1 = ys - y0f, wx1 = xs - x0f;
        float wy0 = 1.f - wy1, wx0 = 1.f - wx1;
        int o = (int)y0f * TCOLS + (int)x0f;
        float v00 = tile[o],         v01 = tile[o + 1];          // ds_read2
        float v10 = tile[o + TCOLS], v11 = tile[o + TCOLS + 1];  // ds_read2
        float sv = wy0 * (wx0 * v00 + wx1 * v01) + wy1 * (wx0 * v10 + wx1 * v11);
        int k = (n < 4) ? n : n + 1;
        res = fmaf(ak[k], sv, res);
    }
    if (MULCONF) {
        res *= cv;
        dst[(size_t)b * HWP + (y + PAD_T) * WP + (x + PAD_L)] = res;
    } else {
        dst[idx] = res;
    }
}

// Zero both padded buffers (apron must be 0; ws is poisoned 0xAA each launch).
__global__ __launch_bounds__(256) void zero_kernel(float4* __restrict__ p, int n4)
{
    int i = blockIdx.x * blockDim.x + threadIdx.x;
    if (i < n4) p[i] = make_float4(0.f, 0.f, 0.f, 0.f);
}

// fc0[padded interior] = feat_init * conf
__global__ __launch_bounds__(256) void mulpad_kernel(
    const float* __restrict__ a, const float* __restrict__ c, float* __restrict__ o)
{
    int t = threadIdx.x;
    int x = blockIdx.x * 64 + (t & 63);
    int y = blockIdx.y * 4 + (t >> 6);
    int b = blockIdx.z;
    int idx = (b * HH + y) * WW + x;
    o[(size_t)b * HWP + (y + PAD_T) * WP + (x + PAD_L)] = a[idx] * c[idx];
}

extern "C" void kernel_launch(void* const* d_in, const int* in_sizes, int n_in,
                              void* d_out, int out_size, void* d_ws, size_t ws_size,
                              hipStream_t stream)
{
    const float* feat_init  = (const float*)d_in[0];
    const float* guidance   = (const float*)d_in[1];
    const float* confidence = (const float*)d_in[2];
    const float* w_oa       = (const float*)d_in[3];
    const float* b_oa       = (const float*)d_in[4];
    const float* aff_scale  = (const float*)d_in[5];
    float* out = (float*)d_out;

    // Workspace: affp u16[9N] | coordp u32[8N] | fc0p f32[BB*HWP] | fc1p
    const size_t N = (size_t)NPIX;
    unsigned short* affp = (unsigned short*)d_ws;
    unsigned* coordp = (unsigned*)(affp + 9 * N);
    float* fc0 = (float*)(coordp + 8 * N);
    float* fc1 = fc0 + (size_t)BB * HWP;

    const dim3 mgrid(WW / 64, HH / 4, BB);   // (19, 88, 4)
    const int n4 = 2 * BB * HWP / 4;
    zero_kernel<<<(n4 + 255) / 256, 256, 0, stream>>>((float4*)fc0, n4);
    mulpad_kernel<<<mgrid, 256, 0, stream>>>(feat_init, confidence, fc0);
    conv_fused_kernel<<<mgrid, 256, 0, stream>>>(
        guidance, w_oa, b_oa, aff_scale, affp, coordp);

    const int pblocks = (WW / 64) * (HH / 4) * BB;   // 6688
    float* bufs[2] = {fc0, fc1};
    const int T = 18;
    for (int i = 0; i < T; ++i) {
        const float* src = bufs[i & 1];
        if (i < T - 1) {
            float* dst = bufs[(i + 1) & 1];
            prop_step_kernel<true><<<pblocks, 256, 0, stream>>>(
                src, affp, coordp, confidence, dst);
        } else {
            prop_step_kernel<false><<<pblocks, 256, 0, stream>>>(
                src, affp, coordp, confidence, out);
        }
    }
}